// Round 7
// baseline (599.799 us; speedup 1.0000x reference)
//
#include <hip/hip_runtime.h>
#include <hip/hip_bf16.h>

#define HIDN   64
#define NHEADS 8
#define DHEAD  8
#define NLAY   2
#define BB     4
#define SS     12
#define NNODE  512
#define NEDGE  8192
#define XELEMS (BB * SS * NNODE * 3)      // 73728
#define ROWS   (BB * SS * NNODE)          // 24576
#define QSCALE 0.51006967f                // (1/sqrt(8)) * log2(e): exp(x)=exp2(x*log2e)
#define NB     256                        // grid blocks (== CUs, co-resident)
#define NT     512                        // threads per block

typedef unsigned short u16;
typedef unsigned int   u32;
typedef __attribute__((ext_vector_type(4))) float f4;   // indexable float4

__device__ __forceinline__ float b2f(u16 u) {
    union { u32 i; float f; } c; c.i = ((u32)u) << 16; return c.f;
}
// decode element i of a raw input tensor (fl=1 -> fp32, fl=0 -> bf16)
__device__ __forceinline__ float ld(const void* p, int i, int fl) {
    return fl ? ((const float*)p)[i] : b2f(((const u16*)p)[i]);
}

// -------- dtype detection FALLBACK (only if in_sizes is ambiguous) -----------
__global__ void detect_kernel(const u16* __restrict__ x, int* __restrict__ flag) {
    int i0 = blockIdx.x * 256 + threadIdx.x;
    int bad = 0;
    for (int i = i0; i < XELEMS; i += 64 * 256) {
        float v = fabsf(b2f(x[i]));
        if (!(v <= 100.f)) bad = 1;   // catches huge AND NaN
    }
    if (bad) atomicOr(flag, 1);       // flag=1 -> inputs are fp32
}

// -------- grid barrier: sense-reversing, agent-scope (cross-XCD safe) --------
// Safe: 256 blocks <= 256 CUs -> all co-resident. cnt MUST start 0; gen any.
__device__ __forceinline__ void gridbar(int* cnt, int* gen) {
    __syncthreads();
    if (threadIdx.x == 0) {
        int g0 = __hip_atomic_load(gen, __ATOMIC_RELAXED, __HIP_MEMORY_SCOPE_AGENT);
        int a  = __hip_atomic_fetch_add(cnt, 1, __ATOMIC_ACQ_REL, __HIP_MEMORY_SCOPE_AGENT);
        if (a == NB - 1) {
            __hip_atomic_store(cnt, 0, __ATOMIC_RELAXED, __HIP_MEMORY_SCOPE_AGENT);
            __hip_atomic_fetch_add(gen, 1, __ATOMIC_ACQ_REL, __HIP_MEMORY_SCOPE_AGENT);
        } else {
            while (__hip_atomic_load(gen, __ATOMIC_ACQUIRE, __HIP_MEMORY_SCOPE_AGENT) == g0)
                __builtin_amdgcn_s_sleep(1);
        }
    }
    __syncthreads();
}

struct MegaArgs {
    const void* x; const void* Win; const void* bin;
    const void* Wq[2]; const void* bq[2];
    const void* Wk[2]; const void* bk[2];
    const void* Wv[2]; const void* bv[2];
    const void* Wout; const void* bout;
    const int* ei;
    float* wT[2]; float* bp[2];
    int* row_ptr; u16* col_idx;
    float* h; float* q; float* k; float* v;
    void* out;
    int* flag; int* cnt; int* gen;
    int flv;
};

// ---- qkv phase: 768 virtual tiles of 32 rows, 3 per block (balanced). ------
// W (both K-phases) staged ONCE per block: wST[2][192][34] + bS = 53 KB.
// thread = (w = tid>>6 -> 4-row group, c = tid&63 -> col). 4 rows x 3 cols acc.
// FMA order over i identical to prior rounds -> bit-identical.
__device__ void qkv_phase(char* smem, const float* __restrict__ h,
                          const float* __restrict__ wT, const float* __restrict__ bias,
                          float* __restrict__ q, float* __restrict__ k, float* __restrict__ v,
                          int spatial_layout, int tid, int bid) {
    float (*wST)[192][34] = (float (*)[192][34])smem;          // 52224 B
    float* bS = (float*)(smem + 52224);                        // 768 B
    {
        const float4* src = (const float4*)wT;
#pragma unroll
        for (int kk = 0; kk < 6; ++kk) {
            float4 w4 = src[tid + NT * kk];
            int idx = 4 * (tid + NT * kk);       // 0..12284
            int ph = (idx >= 6144) ? 1 : 0;
            int r2 = idx - ph * 6144;
            int j = r2 >> 5, il = r2 & 31;
            *(float2*)&wST[ph][j][il]     = make_float2(w4.x, w4.y);
            *(float2*)&wST[ph][j][il + 2] = make_float2(w4.z, w4.w);
        }
        if (tid < 192) bS[tid] = bias[tid];
    }
    __syncthreads();
    int c = tid & 63, w = tid >> 6;
    int rowoff = __builtin_amdgcn_readfirstlane(w * 4);
    for (int tile = bid; tile < 768; tile += NB) {
        int row0 = tile * 32;
        const float* hw = h + (row0 + rowoff) * 64;
        float acc[3][4];
#pragma unroll
        for (int g = 0; g < 3; ++g) {
            float bb = bS[g * 64 + c];
#pragma unroll
            for (int rr = 0; rr < 4; ++rr) acc[g][rr] = bb;
        }
#pragma unroll
        for (int ph = 0; ph < 2; ++ph) {
#pragma unroll 2
            for (int i0 = 0; i0 < 32; i0 += 4) {
                f4 hv[4];
#pragma unroll
                for (int rr = 0; rr < 4; ++rr)
                    hv[rr] = *(const f4*)(hw + rr * 64 + ph * 32 + i0);
                f4 wv[3];
#pragma unroll
                for (int g = 0; g < 3; ++g) {
                    float2 lo = *(const float2*)&wST[ph][g * 64 + c][i0];
                    float2 hi = *(const float2*)&wST[ph][g * 64 + c][i0 + 2];
                    wv[g] = (f4){lo.x, lo.y, hi.x, hi.y};
                }
#pragma unroll
                for (int ii = 0; ii < 4; ++ii)
#pragma unroll
                    for (int g = 0; g < 3; ++g) {
                        float wf = wv[g][ii];
#pragma unroll
                        for (int rr = 0; rr < 4; ++rr) acc[g][rr] += hv[rr][ii] * wf;
                    }
            }
        }
        if (spatial_layout) {
            int bs = row0 >> 9, n0 = row0 & 511;
            int hd = c >> 3, dh = c & 7;
            long off = ((long)(bs * 8 + hd) * 512 + n0 + rowoff) * 8 + dh;
            float* qp = q + off;
            float* kp = k + off;
            float* vp = v + off;
#pragma unroll
            for (int rr = 0; rr < 4; ++rr) {
                qp[rr * 8] = acc[0][rr] * QSCALE;
                kp[rr * 8] = acc[1][rr];
                vp[rr * 8] = acc[2][rr];
            }
        } else {
            int off = (row0 + rowoff) * 64 + c;
            float* qp = q + off;
            float* kp = k + off;
            float* vp = v + off;
#pragma unroll
            for (int rr = 0; rr < 4; ++rr) {
                qp[rr * 64] = acc[0][rr];
                kp[rr * 64] = acc[1][rr];
                vp[rr * 64] = acc[2][rr];
            }
        }
    }
}

// ---- spatial attention phase: pair-per-block; K/V staged once (32 KB); -----
// both query halves computed by the 512 threads: n = tid.
__device__ void spat_phase(char* smem, const float* __restrict__ qh,
                           const float* __restrict__ kh, const float* __restrict__ vh,
                           const int* __restrict__ row_ptr, const u16* __restrict__ col_idx,
                           float* __restrict__ h, int tid, int bid) {
    float (*Ks)[8] = (float (*)[8])smem;             // [512][8] 16 KB
    float (*Vs)[8] = (float (*)[8])(smem + 16384);   // [512][8] 16 KB
    for (int pair = bid; pair < 384; pair += NB) {
        __syncthreads();   // prior readers of smem done
        const float* kp = kh + pair * (NNODE * 8);
        const float* vp = vh + pair * (NNODE * 8);
        {
            int r = tid;   // one row per thread
            float4 k0 = *(const float4*)(kp + r * 8);
            float4 k1 = *(const float4*)(kp + r * 8 + 4);
            float4 v0 = *(const float4*)(vp + r * 8);
            float4 v1 = *(const float4*)(vp + r * 8 + 4);
            *(float4*)&Ks[r][0] = k0; *(float4*)&Ks[r][4] = k1;
            *(float4*)&Vs[r][0] = v0; *(float4*)&Vs[r][4] = v1;
        }
        __syncthreads();
        int bs = pair >> 3, hd = pair & 7;
        int n = tid;
        const float* qp = qh + (pair * NNODE + n) * 8;
        float4 qa = *(const float4*)qp;
        float4 qc = *(const float4*)(qp + 4);
        int e0 = row_ptr[n], e1 = row_ptr[n + 1];
        float l = 0.f;
        float o0=0.f,o1=0.f,o2=0.f,o3=0.f,o4=0.f,o5=0.f,o6=0.f,o7=0.f;
        for (int e = e0; e < e1; ++e) {
            int m = col_idx[e];
            float4 ka = *(const float4*)&Ks[m][0];
            float4 kc = *(const float4*)&Ks[m][4];
            float s = qa.x*ka.x + qa.y*ka.y + qa.z*ka.z + qa.w*ka.w
                    + qc.x*kc.x + qc.y*kc.y + qc.z*kc.z + qc.w*kc.w;
            float p = exp2f(s);          // q prescaled
            l += p;
            float4 va = *(const float4*)&Vs[m][0];
            float4 vc = *(const float4*)&Vs[m][4];
            o0 += p*va.x; o1 += p*va.y; o2 += p*va.z; o3 += p*va.w;
            o4 += p*vc.x; o5 += p*vc.y; o6 += p*vc.z; o7 += p*vc.w;
        }
        if (e1 == e0) {                  // fully-masked row: uniform mean(V)
            for (int m = 0; m < NNODE; ++m) {
                o0 += Vs[m][0]; o1 += Vs[m][1]; o2 += Vs[m][2]; o3 += Vs[m][3];
                o4 += Vs[m][4]; o5 += Vs[m][5]; o6 += Vs[m][6]; o7 += Vs[m][7];
            }
            l = (float)NNODE;
        }
        float inv = 1.f / l;
        float* op = h + (bs * NNODE + n) * HIDN + hd * 8;
        *(float4*)op       = make_float4(o0*inv, o1*inv, o2*inv, o3*inv);
        *(float4*)(op + 4) = make_float4(o4*inv, o5*inv, o6*inv, o7*inv);
    }
}

// ---- temporal attention phase: task = bid exactly (256 tasks). -------------
__device__ void temp_phase(char* smem, const float* __restrict__ q,
                           const float* __restrict__ k, const float* __restrict__ v,
                           float* __restrict__ h, int tid, int bid) {
    float (*Ks2)[8][68] = (float (*)[8][68])smem;             // 26112 B
    float (*Vs2)[8][68] = (float (*)[8][68])(smem + 26112);   // 26112 B
    int b  = bid >> 6;
    int n0 = (bid & 63) * 8;
#pragma unroll
    for (int j = 0; j < 3; ++j) {
        int fid = tid + NT * j;            // 0..1535
        if (fid < 1536) {
            int tt  = fid >> 7;
            int rem = fid & 127;
            int nl  = rem >> 4;
            int dq  = rem & 15;
            long goff = ((long)((b * SS + tt) * NNODE) + n0 + nl) * HIDN + dq * 4;
            *(float4*)&Ks2[tt][nl][dq * 4] = *(const float4*)(k + goff);
            *(float4*)&Vs2[tt][nl][dq * 4] = *(const float4*)(v + goff);
        }
    }
    __syncthreads();
#pragma unroll
    for (int rep = 0; rep < 2; ++rep) {
        int o = tid + rep * NT;
        if (o >= 768) break;
        int hd = o & 7, nl = (o >> 3) & 7, sq = o >> 6;   // sq 0..11
        const float* qp = q + ((long)((b * SS + sq) * NNODE) + n0 + nl) * HIDN + hd * 8;
        float4 qa = *(const float4*)qp;
        float4 qc = *(const float4*)(qp + 4);
        float s[SS];
#pragma unroll
        for (int tt = 0; tt < SS; ++tt) {
            float4 ka = *(const float4*)&Ks2[tt][nl][hd * 8];
            float4 kc = *(const float4*)&Ks2[tt][nl][hd * 8 + 4];
            s[tt] = (qa.x * ka.x + qa.y * ka.y + qa.z * ka.z + qa.w * ka.w +
                     qc.x * kc.x + qc.y * kc.y + qc.z * kc.z + qc.w * kc.w) * QSCALE;
        }
        float mx = s[0];
#pragma unroll
        for (int tt = 1; tt < SS; ++tt) mx = fmaxf(mx, s[tt]);
        float l = 0.f;
#pragma unroll
        for (int tt = 0; tt < SS; ++tt) { s[tt] = exp2f(s[tt] - mx); l += s[tt]; }
        float a0=0.f,a1=0.f,a2=0.f,a3=0.f,a4=0.f,a5=0.f,a6=0.f,a7=0.f;
#pragma unroll
        for (int tt = 0; tt < SS; ++tt) {
            float4 va = *(const float4*)&Vs2[tt][nl][hd * 8];
            float4 vc = *(const float4*)&Vs2[tt][nl][hd * 8 + 4];
            float e = s[tt];
            a0 += e * va.x; a1 += e * va.y; a2 += e * va.z; a3 += e * va.w;
            a4 += e * vc.x; a5 += e * vc.y; a6 += e * vc.z; a7 += e * vc.w;
        }
        float inv = 1.f / l;
        float* op = h + ((long)((b * SS + sq) * NNODE) + n0 + nl) * HIDN + hd * 8;
        *(float4*)op       = make_float4(a0 * inv, a1 * inv, a2 * inv, a3 * inv);
        *(float4*)(op + 4) = make_float4(a4 * inv, a5 * inv, a6 * inv, a7 * inv);
    }
}

// ================================ MEGA =======================================
__global__ __launch_bounds__(NT) void mega_kernel(MegaArgs a) {
    __shared__ __align__(16) char smem[53248];
    int tid = threadIdx.x, bid = blockIdx.x;
    int fl = (a.flv >= 0) ? a.flv : (*a.flag != 0);
    int gid = bid * NT + tid;

    // ---------- phase 0: prep (input proj + pack + mask/CSR) ----------
    for (int id = gid; id < 196608; id += NB * NT) {
        int base = id * 8;
        int row = base >> 6, j0 = base & 63;
        float x0 = ld(a.x, row * 3, fl);
        float x1 = ld(a.x, row * 3 + 1, fl);
        float x2 = ld(a.x, row * 3 + 2, fl);
        float o[8];
#pragma unroll
        for (int jj = 0; jj < 8; ++jj) {
            int j = j0 + jj;
            o[jj] = ld(a.bin, j, fl) + x0 * ld(a.Win, j * 3, fl)
                  + x1 * ld(a.Win, j * 3 + 1, fl) + x2 * ld(a.Win, j * 3 + 2, fl);
        }
        *(float4*)&a.h[base]     = make_float4(o[0], o[1], o[2], o[3]);
        *(float4*)&a.h[base + 4] = make_float4(o[4], o[5], o[6], o[7]);
    }
    if (gid < 49152) {
        int u = gid;
        int p = u / 24576;
        int rem = u - p * 24576;
        int l = rem / 12288;
        int t = rem - l * 12288;
        int ph   = (t >= 6144) ? 1 : 0;
        int r2   = t - ph * 6144;
        int j    = r2 >> 5;
        int iloc = r2 & 31;
        int i    = ph * 32 + iloc;
        int c = j >> 6, cc = j & 63;
        const void* W = (c == 0) ? a.Wq[p] : (c == 1) ? a.Wk[p] : a.Wv[p];
        a.wT[p][l * 12288 + t] = ld(W, l * 4096 + cc * 64 + i, fl);
        if (ph == 0 && iloc == 0) {
            const void* B = (c == 0) ? a.bq[p] : (c == 1) ? a.bk[p] : a.bv[p];
            a.bp[p][l * 192 + j] = ld(B, l * 64 + cc, fl);
        }
    }
    if (bid == NB - 1) {
        u32* msk = (u32*)smem;               // 32 KB
        int* sc  = (int*)(smem + 32768);     // 2 KB
        for (int i = tid; i < NNODE * 16; i += NT) msk[i] = 0;
        __syncthreads();
        for (int e = tid; e < NEDGE; e += NT) {
            int r = a.ei[e];
            int m = a.ei[NEDGE + e];
            atomicOr(&msk[r * 16 + (m >> 5)], 1u << (m & 31));
        }
        __syncthreads();
        int n = tid;
        if (n < 512) {
            u32 w[16];
            int d = 0;
#pragma unroll
            for (int i = 0; i < 16; ++i) { w[i] = msk[n * 16 + i]; d += __popc(w[i]); }
            sc[n] = d;
            __syncthreads();
            for (int s = 1; s < 512; s <<= 1) {
                int vv = (n >= s) ? sc[n - s] : 0;
                __syncthreads();
                sc[n] += vv;
                __syncthreads();
            }
            int excl = sc[n] - d;
            a.row_ptr[n] = excl;
            if (n == 511) a.row_ptr[512] = sc[511];
            int base = excl;
#pragma unroll
            for (int i = 0; i < 16; ++i) {
                u32 m = w[i];
                while (m) {
                    int b = __ffs(m) - 1;
                    m &= m - 1;
                    a.col_idx[base++] = (u16)(i * 32 + b);
                }
            }
        }
    }
    gridbar(a.cnt, a.gen);

    // ---------- layers ----------
    for (int l = 0; l < NLAY; ++l) {
        qkv_phase(smem, a.h, a.wT[0] + l * 12288, a.bp[0] + l * 192,
                  a.q, a.k, a.v, 1, tid, bid);
        gridbar(a.cnt, a.gen);
        spat_phase(smem, a.q, a.k, a.v, a.row_ptr, a.col_idx, a.h, tid, bid);
        gridbar(a.cnt, a.gen);
        qkv_phase(smem, a.h, a.wT[1] + l * 12288, a.bp[1] + l * 192,
                  a.q, a.k, a.v, 0, tid, bid);
        gridbar(a.cnt, a.gen);
        temp_phase(smem, a.q, a.k, a.v, a.h, tid, bid);
        gridbar(a.cnt, a.gen);
    }

    // ---------- out projection ----------
    if (gid < BB * NNODE * 3) {
        int t = gid;
        int c  = t % 3;
        int bn = t / 3;
        int n  = bn & (NNODE - 1);
        int bb = bn >> 9;
        const float* hp = a.h + ((bb * SS + (SS - 1)) * NNODE + n) * HIDN;
        float acc = ld(a.bout, c, fl);
#pragma unroll
        for (int i = 0; i < HIDN; i += 4) {
            float4 h4 = *(const float4*)(hp + i);
            acc += h4.x * ld(a.Wout, c * 64 + i,     fl) + h4.y * ld(a.Wout, c * 64 + i + 1, fl)
                 + h4.z * ld(a.Wout, c * 64 + i + 2, fl) + h4.w * ld(a.Wout, c * 64 + i + 3, fl);
        }
        if (fl) ((float*)a.out)[t] = acc;
        else    ((__hip_bfloat16*)a.out)[t] = __float2bfloat16(acc);
    }
}

extern "C" void kernel_launch(void* const* d_in, const int* in_sizes, int n_in,
                              void* d_out, int out_size, void* d_ws, size_t ws_size,
                              hipStream_t stream) {
    const int* ei = (const int*)d_in[1];

    float* ws = (float*)d_ws;
    int*   iws     = (int*)ws;
    int*   flag    = iws;                         // ws[0]
    int*   cnt     = iws + 1;                     // ws[1]
    int*   gen     = iws + 2;                     // ws[2]
    int*   row_ptr = (int*)(ws + 64);             // 513 ints (reserve 576)
    u16*   col_idx = (u16*)(ws + 640);            // 8192 u16 (4096 float slots)
    float* wTs   = ws + 640 + 4096;               // 2*12288
    float* wTt   = wTs + 24576;                   // 2*12288
    float* bsp   = wTt + 24576;                   // 2*192
    float* btp   = bsp + 384;                     // 2*192
    float* hbuf  = btp + 384;                     // ROWS*64 each
    float* qbuf  = hbuf + ROWS * HIDN;
    float* kbuf  = qbuf + ROWS * HIDN;
    float* vbuf  = kbuf + ROWS * HIDN;

    // dtype from host-visible byte sizes; runtime-detect only if ambiguous
    int flv = -1;
    if (in_sizes) {
        if (in_sizes[0] == XELEMS * 2) flv = 0;        // bf16
        else if (in_sizes[0] == XELEMS * 4) flv = 1;   // fp32
    }
    (void)hipMemsetAsync(iws, 0, 12, stream);          // flag, cnt, gen = 0
    if (flv < 0) {
        detect_kernel<<<64, 256, 0, stream>>>((const u16*)d_in[0], flag);
    }

    MegaArgs a;
    a.x = d_in[0]; a.Win = d_in[2]; a.bin = d_in[3];
    a.Wq[0] = d_in[4];  a.bq[0] = d_in[5];
    a.Wk[0] = d_in[6];  a.bk[0] = d_in[7];
    a.Wv[0] = d_in[8];  a.bv[0] = d_in[9];
    a.Wq[1] = d_in[10]; a.bq[1] = d_in[11];
    a.Wk[1] = d_in[12]; a.bk[1] = d_in[13];
    a.Wv[1] = d_in[14]; a.bv[1] = d_in[15];
    a.Wout = d_in[16]; a.bout = d_in[17];
    a.ei = ei;
    a.wT[0] = wTs; a.bp[0] = bsp;
    a.wT[1] = wTt; a.bp[1] = btp;
    a.row_ptr = row_ptr; a.col_idx = col_idx;
    a.h = hbuf; a.q = qbuf; a.k = kbuf; a.v = vbuf;
    a.out = d_out;
    a.flag = flag; a.cnt = cnt; a.gen = gen;
    a.flv = flv;

    mega_kernel<<<NB, NT, 0, stream>>>(a);
}

// Round 8
// 231.784 us; speedup vs baseline: 2.5878x; 2.5878x over previous
//
#include <hip/hip_runtime.h>
#include <hip/hip_bf16.h>

#define HIDN   64
#define NHEADS 8
#define DHEAD  8
#define NLAY   2
#define BB     4
#define SS     12
#define NNODE  512
#define NEDGE  8192
#define XELEMS (BB * SS * NNODE * 3)      // 73728
#define ROWS   (BB * SS * NNODE)          // 24576
#define QSCALE 0.51006967f                // (1/sqrt(8)) * log2(e): exp(x)=exp2(x*log2e)

typedef unsigned short u16;
typedef unsigned int   u32;
typedef __attribute__((ext_vector_type(4))) float f4;   // indexable float4

__device__ __forceinline__ float b2f(u16 u) {
    union { u32 i; float f; } c; c.i = ((u32)u) << 16; return c.f;
}
// decode element i of a raw input tensor (fl=1 -> fp32, fl=0 -> bf16)
__device__ __forceinline__ float ld(const void* p, int i, int fl) {
    return fl ? ((const float*)p)[i] : b2f(((const u16*)p)[i]);
}

// -------- dtype detection FALLBACK (only if in_sizes is ambiguous) -----------
__global__ void detect_kernel(const u16* __restrict__ x, int* __restrict__ flag) {
    int i0 = blockIdx.x * 256 + threadIdx.x;
    int bad = 0;
    for (int i = i0; i < XELEMS; i += 64 * 256) {
        float v = fabsf(b2f(x[i]));
        if (!(v <= 100.f)) bad = 1;   // catches huge AND NaN
    }
    if (bad) atomicOr(flag, 1);       // flag=1 -> inputs are fp32
}

// ---------------- PREP mega-kernel: input_proj + weight packV2 + mask/CSR ----
// grid = 384 (proj) + 96 (pack) + 1 (mask+csr) = 481 blocks x 512 threads.
// packV2 dest layout: wT[p][l][ph][ib][j][4]  (ph=K-half, ib=i/4 in half,
// j=col 0..191, last = i%4). Makes the GEMM's W read a lane-consecutive
// coalesced global float4 -> no LDS staging needed in qkv.
struct PrepArgs {
    const void* x; const void* Win; const void* bin; float* h;
    const void* Wq[2]; const void* bq[2];
    const void* Wk[2]; const void* bk[2];
    const void* Wv[2]; const void* bv[2];
    float* wT[2]; float* bp[2];
    const int* ei; int* row_ptr; u16* col_idx;
};
__global__ __launch_bounds__(512) void prep_kernel(PrepArgs a, const int* __restrict__ flagp) {
    __shared__ u32 msk[NNODE * 16];   // 32 KB (only used by last block)
    __shared__ int sc[512];
    int fl = (*flagp != 0);
    int bid = blockIdx.x;
    int tid = threadIdx.x;
    if (bid < 384) {
        // ---- input projection: 8 consecutive h elems per thread
        int base = (bid * 512 + tid) * 8;     // row*64 + j0
        int row = base >> 6, j0 = base & 63;
        float x0 = ld(a.x, row * 3, fl);
        float x1 = ld(a.x, row * 3 + 1, fl);
        float x2 = ld(a.x, row * 3 + 2, fl);
        float o[8];
#pragma unroll
        for (int jj = 0; jj < 8; ++jj) {
            int j = j0 + jj;
            o[jj] = ld(a.bin, j, fl) + x0 * ld(a.Win, j * 3, fl)
                  + x1 * ld(a.Win, j * 3 + 1, fl) + x2 * ld(a.Win, j * 3 + 2, fl);
        }
        *(float4*)&a.h[base]     = make_float4(o[0], o[1], o[2], o[3]);
        *(float4*)&a.h[base + 4] = make_float4(o[4], o[5], o[6], o[7]);
        return;
    }
    if (bid < 480) {
        // ---- weight packV2
        int u = (bid - 384) * 512 + tid;  // 0..49151
        int p = u / 24576;
        int rem = u - p * 24576;
        int l = rem / 12288;
        int t = rem - l * 12288;          // linear DEST index
        int ph = t / 6144;
        int r  = t - ph * 6144;
        int ib = r / 768;                 // 0..7
        int r2 = r - ib * 768;
        int j  = r2 >> 2;                 // 0..191
        int i2 = r2 & 3;
        int i  = ph * 32 + ib * 4 + i2;   // 0..63
        int cg = j >> 6, cc = j & 63;
        const void* W = (cg == 0) ? a.Wq[p] : (cg == 1) ? a.Wk[p] : a.Wv[p];
        a.wT[p][l * 12288 + t] = ld(W, l * 4096 + cc * 64 + i, fl);
        // ---- bias: first 768 u's cover 2p x 2l x 192
        if (u < 768) {
            int p2 = u / 384;
            int r3 = u - p2 * 384;
            int l2 = r3 / 192;
            int j2 = r3 - l2 * 192;
            int cg2 = j2 >> 6;
            const void* B = (cg2 == 0) ? a.bq[p2] : (cg2 == 1) ? a.bk[p2] : a.bv[p2];
            a.bp[p2][l2 * 192 + j2] = ld(B, l2 * 64 + (j2 & 63), fl);
        }
        return;
    }
    // ---- mask bitset (LDS) + CSR build, one 512-thread block
    for (int i = tid; i < NNODE * 16; i += 512) msk[i] = 0;
    __syncthreads();
    for (int e = tid; e < NEDGE; e += 512) {
        int r = a.ei[e];           // query row
        int m = a.ei[NEDGE + e];   // key col
        atomicOr(&msk[r * 16 + (m >> 5)], 1u << (m & 31));
    }
    __syncthreads();
    int n = tid;   // 0..511
    u32 w[16];
    int d = 0;
#pragma unroll
    for (int i = 0; i < 16; ++i) { w[i] = msk[n * 16 + i]; d += __popc(w[i]); }
    sc[n] = d;
    __syncthreads();
    for (int s = 1; s < 512; s <<= 1) {
        int v = (n >= s) ? sc[n - s] : 0;
        __syncthreads();
        sc[n] += v;
        __syncthreads();
    }
    int excl = sc[n] - d;
    a.row_ptr[n] = excl;
    if (n == 511) a.row_ptr[512] = sc[511];
    int base = excl;
#pragma unroll
    for (int i = 0; i < 16; ++i) {
        u32 m = w[i];
        while (m) {
            int b = __ffs(m) - 1;
            m &= m - 1;
            a.col_idx[base++] = (u16)(i * 32 + b);
        }
    }
}

// ---------------- fused q/k/v GEMM v5: ZERO LDS, max occupancy ---------------
// 256 threads = (wave w = row octet, lane c = col). W read directly from
// global (packV2 layout -> lane-consecutive float4, L1/L2-hot 48 KB).
// h read via wave-uniform scalar loads. No LDS -> occupancy VGPR-bound only.
// FMA order over i identical to v3/v4 -> bit-identical outputs.
__global__ __launch_bounds__(256, 4) void qkv_gemm_kernel(
    const float* __restrict__ h, const float* __restrict__ wT,
    const float* __restrict__ bias,
    float* __restrict__ q, float* __restrict__ k, float* __restrict__ v,
    int spatial_layout) {
    int t = threadIdx.x;
    int row0 = blockIdx.x * 32;
    int c = t & 63, w = t >> 6;
    int rowoff = __builtin_amdgcn_readfirstlane(w * 8);   // uniform row base
    const float* hw = h + (row0 + rowoff) * 64;
    float acc[3][8];
#pragma unroll
    for (int g = 0; g < 3; ++g) {
        float bb = bias[g * 64 + c];
#pragma unroll
        for (int rr = 0; rr < 8; ++rr) acc[g][rr] = bb;
    }
#pragma unroll
    for (int ph = 0; ph < 2; ++ph) {
#pragma unroll 2
        for (int i0 = 0; i0 < 32; i0 += 4) {
            f4 hv[8];
#pragma unroll
            for (int rr = 0; rr < 8; ++rr)
                hv[rr] = *(const f4*)(hw + rr * 64 + ph * 32 + i0);
            f4 wv[3];
#pragma unroll
            for (int g = 0; g < 3; ++g)
                wv[g] = *(const f4*)(wT + ph * 6144 + (((i0 >> 2) * 192) + g * 64 + c) * 4);
#pragma unroll
            for (int ii = 0; ii < 4; ++ii)
#pragma unroll
                for (int g = 0; g < 3; ++g) {
                    float wf = wv[g][ii];
#pragma unroll
                    for (int rr = 0; rr < 8; ++rr) acc[g][rr] += hv[rr][ii] * wf;
                }
        }
    }
    // ---- epilogue: lane-consecutive stores
    if (spatial_layout) {
        int bs = row0 >> 9, n0 = row0 & 511;
        int hd = c >> 3, dh = c & 7;
        long off = ((long)(bs * 8 + hd) * 512 + n0 + rowoff) * 8 + dh;
        float* qp = q + off;
        float* kp = k + off;
        float* vp = v + off;
#pragma unroll
        for (int rr = 0; rr < 8; ++rr) {
            qp[rr * 8] = acc[0][rr] * QSCALE;
            kp[rr * 8] = acc[1][rr];
            vp[rr * 8] = acc[2][rr];
        }
    } else {
        int off = (row0 + rowoff) * 64 + c;
        float* qp = q + off;
        float* kp = k + off;
        float* vp = v + off;
#pragma unroll
        for (int rr = 0; rr < 8; ++rr) {
            qp[rr * 64] = acc[0][rr];
            kp[rr * 64] = acc[1][rr];
            vp[rr * 64] = acc[2][rr];
        }
    }
}

// ---------------- spatial attention: SPARSE (avg degree 16/512) --------------
__global__ __launch_bounds__(256) void spatial_attn_kernel(
    const float* __restrict__ qh, const float* __restrict__ kh, const float* __restrict__ vh,
    const int* __restrict__ row_ptr, const u16* __restrict__ col_idx,
    float* __restrict__ h) {
    __shared__ __align__(16) float Ks[NNODE][8];   // 16 KB
    __shared__ __align__(16) float Vs[NNODE][8];   // 16 KB
    int bxx = blockIdx.x;
    int pair = bxx >> 1, halfq = bxx & 1;
    int bs = pair >> 3, hd = pair & 7;      // bs = b*S+s in [0,48)
    const float* kp = kh + pair * (NNODE * 8);
    const float* vp = vh + pair * (NNODE * 8);
    int t = threadIdx.x;
#pragma unroll
    for (int i = 0; i < 2; ++i) {
        int r = t + 256 * i;
        float4 k0 = *(const float4*)(kp + r * 8);
        float4 k1 = *(const float4*)(kp + r * 8 + 4);
        float4 v0 = *(const float4*)(vp + r * 8);
        float4 v1 = *(const float4*)(vp + r * 8 + 4);
        *(float4*)&Ks[r][0] = k0; *(float4*)&Ks[r][4] = k1;
        *(float4*)&Vs[r][0] = v0; *(float4*)&Vs[r][4] = v1;
    }
    __syncthreads();
    int n = halfq * 256 + t;
    const float* qp = qh + (pair * NNODE + n) * 8;
    float4 qa = *(const float4*)qp;
    float4 qc = *(const float4*)(qp + 4);
    int e0 = row_ptr[n], e1 = row_ptr[n + 1];
    float l = 0.f;
    float o0=0.f,o1=0.f,o2=0.f,o3=0.f,o4=0.f,o5=0.f,o6=0.f,o7=0.f;
    for (int e = e0; e < e1; ++e) {
        int m = col_idx[e];
        float4 ka = *(const float4*)&Ks[m][0];
        float4 kc = *(const float4*)&Ks[m][4];
        float s = qa.x*ka.x + qa.y*ka.y + qa.z*ka.z + qa.w*ka.w
                + qc.x*kc.x + qc.y*kc.y + qc.z*kc.z + qc.w*kc.w;
        float p = exp2f(s);          // q prescaled by (1/sqrt8)*log2e
        l += p;
        float4 va = *(const float4*)&Vs[m][0];
        float4 vc = *(const float4*)&Vs[m][4];
        o0 += p*va.x; o1 += p*va.y; o2 += p*va.z; o3 += p*va.w;
        o4 += p*vc.x; o5 += p*vc.y; o6 += p*vc.z; o7 += p*vc.w;
    }
    if (e1 == e0) {                  // fully-masked row: uniform mean(V)
        for (int m = 0; m < NNODE; ++m) {
            o0 += Vs[m][0]; o1 += Vs[m][1]; o2 += Vs[m][2]; o3 += Vs[m][3];
            o4 += Vs[m][4]; o5 += Vs[m][5]; o6 += Vs[m][6]; o7 += Vs[m][7];
        }
        l = (float)NNODE;
    }
    float inv = 1.f / l;
    float* op = h + (bs * NNODE + n) * HIDN + hd * 8;
    *(float4*)op       = make_float4(o0*inv, o1*inv, o2*inv, o3*inv);
    *(float4*)(op + 4) = make_float4(o4*inv, o5*inv, o6*inv, o7*inv);
}

// ---------------- temporal attention v3: conflict-free LDS (stride 9) --------
// grid 256 = (b [4]) x (node chunk of 8 [64]); 768 threads = (sq, nl, hd).
// K/V rows [tt][r=nl*8+hd][9]: bank = (9r+dq) mod 32, gcd(9,32)=1 -> 2-way free
// on both the b32 reads (lane=r) and staging writes. Same expression order as
// v2 -> bit-identical.
__global__ __launch_bounds__(768) void temporal_attn_kernel(
    const float* __restrict__ q, const float* __restrict__ k, const float* __restrict__ v,
    float* __restrict__ h) {
    __shared__ float Ks2[SS][64][9];   // 27648 B
    __shared__ float Vs2[SS][64][9];   // 27648 B
    int b  = blockIdx.x >> 6;
    int n0 = (blockIdx.x & 63) * 8;
    int t = threadIdx.x;
    // stage: thread t owns (tt = t>>6, r = t&63): one 8-float row of K and V
    {
        int tt = t >> 6, r = t & 63;
        int nl = r >> 3, hd = r & 7;
        long goff = ((long)((b * SS + tt) * NNODE) + n0 + nl) * HIDN + hd * 8;
        float4 k0 = *(const float4*)(k + goff);
        float4 k1 = *(const float4*)(k + goff + 4);
        float4 v0 = *(const float4*)(v + goff);
        float4 v1 = *(const float4*)(v + goff + 4);
        float* kd = &Ks2[tt][r][0];
        float* vd = &Vs2[tt][r][0];
        kd[0]=k0.x; kd[1]=k0.y; kd[2]=k0.z; kd[3]=k0.w;
        kd[4]=k1.x; kd[5]=k1.y; kd[6]=k1.z; kd[7]=k1.w;
        vd[0]=v0.x; vd[1]=v0.y; vd[2]=v0.z; vd[3]=v0.w;
        vd[4]=v1.x; vd[5]=v1.y; vd[6]=v1.z; vd[7]=v1.w;
    }
    __syncthreads();
    int hd = t & 7, nl = (t >> 3) & 7, sq = t >> 6;   // sq 0..11
    int r = t & 63;
    const float* qp = q + ((long)((b * SS + sq) * NNODE) + n0 + nl) * HIDN + hd * 8;
    float4 qa = *(const float4*)qp;
    float4 qc = *(const float4*)(qp + 4);
    float s[SS];
#pragma unroll
    for (int tt = 0; tt < SS; ++tt) {
        const float* kd = &Ks2[tt][r][0];
        s[tt] = (qa.x * kd[0] + qa.y * kd[1] + qa.z * kd[2] + qa.w * kd[3] +
                 qc.x * kd[4] + qc.y * kd[5] + qc.z * kd[6] + qc.w * kd[7]) * QSCALE;
    }
    float mx = s[0];
#pragma unroll
    for (int tt = 1; tt < SS; ++tt) mx = fmaxf(mx, s[tt]);
    float l = 0.f;
#pragma unroll
    for (int tt = 0; tt < SS; ++tt) { s[tt] = exp2f(s[tt] - mx); l += s[tt]; }
    float a0=0.f,a1=0.f,a2=0.f,a3=0.f,a4=0.f,a5=0.f,a6=0.f,a7=0.f;
#pragma unroll
    for (int tt = 0; tt < SS; ++tt) {
        const float* vd = &Vs2[tt][r][0];
        float e = s[tt];
        a0 += e * vd[0]; a1 += e * vd[1]; a2 += e * vd[2]; a3 += e * vd[3];
        a4 += e * vd[4]; a5 += e * vd[5]; a6 += e * vd[6]; a7 += e * vd[7];
    }
    float inv = 1.f / l;
    float* op = h + ((long)((b * SS + sq) * NNODE) + n0 + nl) * HIDN + hd * 8;
    *(float4*)op       = make_float4(a0 * inv, a1 * inv, a2 * inv, a3 * inv);
    *(float4*)(op + 4) = make_float4(a4 * inv, a5 * inv, a6 * inv, a7 * inv);
}

// ---------------- output projection: h[:, S-1] @ raw WoutT + raw bout --------
__global__ void out_proj_kernel(const float* __restrict__ h, const void* __restrict__ W,
                                const void* __restrict__ b, void* __restrict__ out,
                                const int* __restrict__ flagp) {
    int fl = (*flagp != 0);
    int t = blockIdx.x * blockDim.x + threadIdx.x;
    if (t >= BB * NNODE * 3) return;
    int c  = t % 3;
    int bn = t / 3;
    int n  = bn & (NNODE - 1);
    int bb = bn >> 9;
    const float* hp = h + ((bb * SS + (SS - 1)) * NNODE + n) * HIDN;
    float a = ld(b, c, fl);
#pragma unroll
    for (int i = 0; i < HIDN; i += 4) {
        float4 h4 = *(const float4*)(hp + i);
        a += h4.x * ld(W, c * 64 + i,     fl) + h4.y * ld(W, c * 64 + i + 1, fl)
           + h4.z * ld(W, c * 64 + i + 2, fl) + h4.w * ld(W, c * 64 + i + 3, fl);
    }
    if (fl) ((float*)out)[t] = a;
    else    ((__hip_bfloat16*)out)[t] = __float2bfloat16(a);
}

extern "C" void kernel_launch(void* const* d_in, const int* in_sizes, int n_in,
                              void* d_out, int out_size, void* d_ws, size_t ws_size,
                              hipStream_t stream) {
    const int* ei = (const int*)d_in[1];

    float* ws = (float*)d_ws;
    int*   flag    = (int*)ws;                    // 64 floats reserved
    int*   row_ptr = (int*)(ws + 64);             // 513 ints (reserve 576)
    u16*   col_idx = (u16*)(ws + 640);            // 8192 u16 (4096 float slots)
    float* wTs   = ws + 640 + 4096;               // 2*12288
    float* wTt   = wTs + 24576;                   // 2*12288
    float* bsp   = wTt + 24576;                   // 2*192
    float* btp   = bsp + 384;                     // 2*192
    float* hbuf  = btp + 384;                     // ROWS*64 each
    float* qbuf  = hbuf + ROWS * HIDN;
    float* kbuf  = qbuf + ROWS * HIDN;
    float* vbuf  = kbuf + ROWS * HIDN;

    // dtype from host-visible byte sizes; runtime-detect only if ambiguous
    int flv = -1;
    if (in_sizes) {
        if (in_sizes[0] == XELEMS * 2) flv = 0;        // bf16
        else if (in_sizes[0] == XELEMS * 4) flv = 1;   // fp32
    }
    if (flv >= 0) {
        (void)hipMemsetAsync(flag, flv, sizeof(int), stream);
    } else {
        (void)hipMemsetAsync(flag, 0, sizeof(int), stream);
        detect_kernel<<<64, 256, 0, stream>>>((const u16*)d_in[0], flag);
    }

    PrepArgs pr;
    pr.x = d_in[0]; pr.Win = d_in[2]; pr.bin = d_in[3]; pr.h = hbuf;
    pr.Wq[0] = d_in[4];  pr.bq[0] = d_in[5];
    pr.Wk[0] = d_in[6];  pr.bk[0] = d_in[7];
    pr.Wv[0] = d_in[8];  pr.bv[0] = d_in[9];
    pr.Wq[1] = d_in[10]; pr.bq[1] = d_in[11];
    pr.Wk[1] = d_in[12]; pr.bk[1] = d_in[13];
    pr.Wv[1] = d_in[14]; pr.bv[1] = d_in[15];
    pr.wT[0] = wTs; pr.bp[0] = bsp;
    pr.wT[1] = wTt; pr.bp[1] = btp;
    pr.ei = ei; pr.row_ptr = row_ptr; pr.col_idx = col_idx;
    prep_kernel<<<384 + 96 + 1, 512, 0, stream>>>(pr, flag);

    const int GEMM_BLOCKS = ROWS / 32;                       // 768
    for (int l = 0; l < NLAY; ++l) {
        // spatial
        qkv_gemm_kernel<<<GEMM_BLOCKS, 256, 0, stream>>>(
            hbuf, wTs + l * 12288, bsp + l * 192, qbuf, kbuf, vbuf, 1);
        spatial_attn_kernel<<<BB * SS * NHEADS * 2, 256, 0, stream>>>(
            qbuf, kbuf, vbuf, row_ptr, col_idx, hbuf);
        // temporal
        qkv_gemm_kernel<<<GEMM_BLOCKS, 256, 0, stream>>>(
            hbuf, wTt + l * 12288, btp + l * 192, qbuf, kbuf, vbuf, 0);
        temporal_attn_kernel<<<BB * (NNODE / 8), 768, 0, stream>>>(
            qbuf, kbuf, vbuf, hbuf);
    }
    out_proj_kernel<<<(BB * NNODE * 3 + 255) / 256, 256, 0, stream>>>(
        hbuf, d_in[16], d_in[17], d_out, flag);
}